// Round 8
// baseline (69.875 us; speedup 1.0000x reference)
//
#include <hip/hip_runtime.h>

#define H 384
#define W 384
#define C 19
#define NB 4
#define HP 382               // H - K + 1
#define HW (H * W)
#define CHW (C * HW)
#define TOTAL_TERMS 47279376.0f   // NB * 81 * HP*HP

#define NIG (NB * 378 * 94)         // 142128 interior pixel-groups
#define NEG (NB * (6 * 96 + 378 * 2))  // 5328 edge pixel-groups
#define IBLOCKS ((NIG + 127) / 128)    // 1111 (128 groups/block: 2 parities x 64)
#define EBLOCKS ((NEG * 2 + 255) / 256) // 42

// number of kernel-offsets a in [0,2] with 0 <= a+d <= 2 and 0 <= p-a <= HP-1
__device__ __forceinline__ int multv(int p, int d) {
    int lo = max(max(0, -d), p - (HP - 1));
    int hi = min(min(2, 2 - d), p);
    return max(0, hi - lo + 1);
}

__device__ __forceinline__ float bce_fast(float x, float y) {
    // max(x,0) - x*y + log1p(exp(-|x|)), fast-math variant
    float t = __expf(-fabsf(x));
    return fmaxf(x, 0.0f) - x * y + __logf(1.0f + t);
}

// ---------------- interior kernel: py in [2,379], px0 in [4,376] ------------
// All offsets compile-time; all weights literal. Per block: 128 groups,
// 2 wave-parities: par0 = offsets (0,0),(0,1),(0,2),(2,-2..2) [rows 0,2];
// par1 = offsets (1,-2..2) [row 1 (+own row-0 f4)].
__global__ __launch_bounds__(256) void aff_interior(
        const float* __restrict__ logits,
        const int* __restrict__ labels,
        float* __restrict__ partial) {
    const int t    = threadIdx.x;
    const int lane = t & 63;
    const int wid  = t >> 6;
    const int par  = wid & 1;

    int gi = blockIdx.x * 128 + (wid >> 1) * 64 + lane;
    const bool valid = gi < NIG;
    gi = min(gi, NIG - 1);

    const int n   = gi / (378 * 94);
    const int r   = gi % (378 * 94);
    const int py  = 2 + r / 94;
    const int px0 = 4 + 4 * (r % 94);

    // base pointers at column px0-4 (16B-aligned)
    const float* plane = logits + (size_t)n * CHW + py * W + (px0 - 4);
    const int*   lb    = labels + (size_t)n * HW + py * W + (px0 - 4);

    float total = 0.0f;

    if (par == 0) {
        float acc[32];
#pragma unroll
        for (int k = 0; k < 32; ++k) acc[k] = 0.0f;

        const float* r0 = plane;
        const float* r2 = plane + 2 * W;
#pragma unroll
        for (int c = 0; c < C; ++c) {
            float a[12], e[12];
            *(float4*)&a[0] = *(const float4*)(r0);
            *(float4*)&a[4] = *(const float4*)(r0 + 4);
            *(float4*)&a[8] = *(const float4*)(r0 + 8);
            *(float4*)&e[0] = *(const float4*)(r2);
            *(float4*)&e[4] = *(const float4*)(r2 + 4);
            *(float4*)&e[8] = *(const float4*)(r2 + 8);
#pragma unroll
            for (int i = 0; i < 4; ++i) {
                const float s = a[4 + i];          // col px0+i
                acc[i * 8 + 0] += s * s;           // (0,0)
                acc[i * 8 + 1] += s * a[5 + i];    // (0,1)
                acc[i * 8 + 2] += s * a[6 + i];    // (0,2)
#pragma unroll
                for (int dxi = 0; dxi < 5; ++dxi)  // (2, dxi-2)
                    acc[i * 8 + 3 + dxi] += s * e[2 + i + dxi];
            }
            r0 += HW; r2 += HW;
        }

        int la[12], ler[12];
        *(int4*)&la[0]  = *(const int4*)(lb);
        *(int4*)&la[4]  = *(const int4*)(lb + 4);
        *(int4*)&la[8]  = *(const int4*)(lb + 8);
        *(int4*)&ler[0] = *(const int4*)(lb + 2 * W);
        *(int4*)&ler[4] = *(const int4*)(lb + 2 * W + 4);
        *(int4*)&ler[8] = *(const int4*)(lb + 2 * W + 8);

        const float W2[5] = {2.0f, 4.0f, 6.0f, 4.0f, 2.0f};  // 2*wy2*wx
#pragma unroll
        for (int i = 0; i < 4; ++i) {
            const int ls = la[4 + i];
            total += 9.0f  * bce_fast(acc[i * 8 + 0], 1.0f);
            total += 12.0f * bce_fast(acc[i * 8 + 1], (ls == la[5 + i]) ? 1.0f : 0.0f);
            total += 6.0f  * bce_fast(acc[i * 8 + 2], (ls == la[6 + i]) ? 1.0f : 0.0f);
#pragma unroll
            for (int dxi = 0; dxi < 5; ++dxi)
                total += W2[dxi] * bce_fast(acc[i * 8 + 3 + dxi],
                                            (ls == ler[2 + i + dxi]) ? 1.0f : 0.0f);
        }
    } else {
        float acc[20];
#pragma unroll
        for (int k = 0; k < 20; ++k) acc[k] = 0.0f;

        const float* r0 = plane;
        const float* r1 = plane + W;
#pragma unroll
        for (int c = 0; c < C; ++c) {
            float sa[4], b[12];
            *(float4*)&sa[0] = *(const float4*)(r0 + 4);   // cols px0..px0+3
            *(float4*)&b[0]  = *(const float4*)(r1);
            *(float4*)&b[4]  = *(const float4*)(r1 + 4);
            *(float4*)&b[8]  = *(const float4*)(r1 + 8);
#pragma unroll
            for (int i = 0; i < 4; ++i) {
                const float s = sa[i];
#pragma unroll
                for (int dxi = 0; dxi < 5; ++dxi)  // (1, dxi-2)
                    acc[i * 5 + dxi] += s * b[2 + i + dxi];
            }
            r0 += HW; r1 += HW;
        }

        int la4[4], lbr[12];
        *(int4*)&la4[0] = *(const int4*)(lb + 4);
        *(int4*)&lbr[0] = *(const int4*)(lb + W);
        *(int4*)&lbr[4] = *(const int4*)(lb + W + 4);
        *(int4*)&lbr[8] = *(const int4*)(lb + W + 8);

        const float W1[5] = {4.0f, 8.0f, 12.0f, 8.0f, 4.0f};  // 2*wy1*wx
#pragma unroll
        for (int i = 0; i < 4; ++i) {
            const int ls = la4[i];
#pragma unroll
            for (int dxi = 0; dxi < 5; ++dxi)
                total += W1[dxi] * bce_fast(acc[i * 5 + dxi],
                                            (ls == lbr[2 + i + dxi]) ? 1.0f : 0.0f);
        }
    }

    if (!valid) total = 0.0f;

#pragma unroll
    for (int off = 32; off > 0; off >>= 1) total += __shfl_down(total, off, 64);
    __shared__ float sm[4];
    if (lane == 0) sm[wid] = total;
    __syncthreads();
    if (t == 0)
        partial[blockIdx.x] = sm[0] + sm[1] + sm[2] + sm[3];
}

// ---------------- edge kernel: generic clamped path (R4 body) ---------------
__global__ __launch_bounds__(256) void aff_edge(
        const float* __restrict__ logits,
        const int* __restrict__ labels,
        float* __restrict__ partial) {
    const int t    = threadIdx.x;
    const int lane = t & 63;
    const int wid  = t >> 6;
    const int par  = wid & 1;

    int ge = blockIdx.x * 128 + (wid >> 1) * 64 + lane;
    const bool valid = ge < NEG;
    ge = min(ge, NEG - 1);

    int n, py, px0;
    if (ge < NB * 576) {                 // rows {0,1,380,381,382,383}, all cols
        n = ge / 576;
        const int rr = ge % 576;
        const int ry = rr / 96;
        py  = (ry < 2) ? ry : ry + 378;
        px0 = 4 * (rr % 96);
    } else {                             // rows [2,379], col-groups {0, 95}
        const int e2 = ge - NB * 576;
        n = e2 / 756;
        const int rr = e2 % 756;
        py  = 2 + rr / 2;
        px0 = (rr & 1) * 380;
    }

    const int x0c = max(0, px0 - 4);
    const int d1  = px0 - x0c;
    const int d2  = min(W - 4, px0 + 4) - x0c;
    const int ro1 = (min(py + 1, H - 1) - py) * W;
    const int ro2 = (min(py + 2, H - 1) - py) * W;

    const float* p0  = logits + (size_t)n * CHW + py * W + x0c;
    const int*   lb0 = labels + (size_t)n * HW + py * W + x0c;

    const int wy0 = multv(py, 0);
    const int wy1 = multv(py, 1);
    const int wy2 = multv(py, 2);

    float total = 0.0f;

    if (par == 0) {
        float acc[32];
#pragma unroll
        for (int k = 0; k < 32; ++k) acc[k] = 0.0f;
#pragma unroll
        for (int c = 0; c < C; ++c) {
            const float* pr = p0 + (size_t)c * HW;
            float a[12], e[12];
            *(float4*)&a[0] = *(const float4*)(pr);
            *(float4*)&a[4] = *(const float4*)(pr + d1);
            *(float4*)&a[8] = *(const float4*)(pr + d2);
            *(float4*)&e[0] = *(const float4*)(pr + ro2);
            *(float4*)&e[4] = *(const float4*)(pr + ro2 + d1);
            *(float4*)&e[8] = *(const float4*)(pr + ro2 + d2);
#pragma unroll
            for (int i = 0; i < 4; ++i) {
                const float s = a[4 + i];
                acc[i * 8 + 0] += s * s;
                acc[i * 8 + 1] += s * a[5 + i];
                acc[i * 8 + 2] += s * a[6 + i];
#pragma unroll
                for (int dxi = 0; dxi < 5; ++dxi)
                    acc[i * 8 + 3 + dxi] += s * e[2 + i + dxi];
            }
        }
        int la[12], ler[12];
        *(int4*)&la[0]  = *(const int4*)(lb0);
        *(int4*)&la[4]  = *(const int4*)(lb0 + d1);
        *(int4*)&la[8]  = *(const int4*)(lb0 + d2);
        *(int4*)&ler[0] = *(const int4*)(lb0 + ro2);
        *(int4*)&ler[4] = *(const int4*)(lb0 + ro2 + d1);
        *(int4*)&ler[8] = *(const int4*)(lb0 + ro2 + d2);
#pragma unroll
        for (int i = 0; i < 4; ++i) {
            const int px = px0 + i;
            int wx[5];
#pragma unroll
            for (int dxi = 0; dxi < 5; ++dxi) wx[dxi] = multv(px, dxi - 2);
            const int ls = la[4 + i];
            total += (float)(wy0 * wx[2]) * bce_fast(acc[i * 8 + 0], 1.0f);
            total += 2.0f * (float)(wy0 * wx[3]) *
                     bce_fast(acc[i * 8 + 1], (ls == la[5 + i]) ? 1.0f : 0.0f);
            total += 2.0f * (float)(wy0 * wx[4]) *
                     bce_fast(acc[i * 8 + 2], (ls == la[6 + i]) ? 1.0f : 0.0f);
#pragma unroll
            for (int dxi = 0; dxi < 5; ++dxi)
                total += 2.0f * (float)(wy2 * wx[dxi]) *
                         bce_fast(acc[i * 8 + 3 + dxi],
                                  (ls == ler[2 + i + dxi]) ? 1.0f : 0.0f);
        }
    } else {
        float acc[20];
#pragma unroll
        for (int k = 0; k < 20; ++k) acc[k] = 0.0f;
#pragma unroll
        for (int c = 0; c < C; ++c) {
            const float* pr = p0 + (size_t)c * HW;
            float sa[4], b[12];
            *(float4*)&sa[0] = *(const float4*)(pr + d1);
            *(float4*)&b[0]  = *(const float4*)(pr + ro1);
            *(float4*)&b[4]  = *(const float4*)(pr + ro1 + d1);
            *(float4*)&b[8]  = *(const float4*)(pr + ro1 + d2);
#pragma unroll
            for (int i = 0; i < 4; ++i) {
                const float s = sa[i];
#pragma unroll
                for (int dxi = 0; dxi < 5; ++dxi)
                    acc[i * 5 + dxi] += s * b[2 + i + dxi];
            }
        }
        int la4[4], lbr[12];
        *(int4*)&la4[0] = *(const int4*)(lb0 + d1);
        *(int4*)&lbr[0] = *(const int4*)(lb0 + ro1);
        *(int4*)&lbr[4] = *(const int4*)(lb0 + ro1 + d1);
        *(int4*)&lbr[8] = *(const int4*)(lb0 + ro1 + d2);
#pragma unroll
        for (int i = 0; i < 4; ++i) {
            const int px = px0 + i;
            int wx[5];
#pragma unroll
            for (int dxi = 0; dxi < 5; ++dxi) wx[dxi] = multv(px, dxi - 2);
            const int ls = la4[i];
#pragma unroll
            for (int dxi = 0; dxi < 5; ++dxi)
                total += 2.0f * (float)(wy1 * wx[dxi]) *
                         bce_fast(acc[i * 5 + dxi],
                                  (ls == lbr[2 + i + dxi]) ? 1.0f : 0.0f);
        }
    }

    if (!valid) total = 0.0f;

#pragma unroll
    for (int off = 32; off > 0; off >>= 1) total += __shfl_down(total, off, 64);
    __shared__ float sm[4];
    if (lane == 0) sm[wid] = total;
    __syncthreads();
    if (t == 0)
        partial[IBLOCKS + blockIdx.x] = sm[0] + sm[1] + sm[2] + sm[3];
}

__global__ __launch_bounds__(256) void reduce_final(
        const float* __restrict__ partial, int n, float* __restrict__ out) {
    float s = 0.0f;
    for (int i = threadIdx.x; i < n; i += 256) s += partial[i];
#pragma unroll
    for (int off = 32; off > 0; off >>= 1) s += __shfl_down(s, off, 64);
    __shared__ float sm[4];
    const int lane = threadIdx.x & 63, wid = threadIdx.x >> 6;
    if (lane == 0) sm[wid] = s;
    __syncthreads();
    if (threadIdx.x == 0)
        out[0] = (sm[0] + sm[1] + sm[2] + sm[3]) / TOTAL_TERMS;
}

extern "C" void kernel_launch(void* const* d_in, const int* in_sizes, int n_in,
                              void* d_out, int out_size, void* d_ws, size_t ws_size,
                              hipStream_t stream) {
    const float* logits = (const float*)d_in[0];
    const int*   labels = (const int*)d_in[1];
    float* out     = (float*)d_out;
    float* partial = (float*)d_ws;   // IBLOCKS + EBLOCKS = 1153 floats

    aff_interior<<<IBLOCKS, 256, 0, stream>>>(logits, labels, partial);
    aff_edge<<<EBLOCKS, 256, 0, stream>>>(logits, labels, partial);
    reduce_final<<<1, 256, 0, stream>>>(partial, IBLOCKS + EBLOCKS, out);
}

// Round 9
// 35.014 us; speedup vs baseline: 1.9956x; 1.9956x over previous
//
#include <hip/hip_runtime.h>

#define H 384
#define W 384
#define C 19
#define NB 4
#define HP 382               // H - K + 1
#define HW (H * W)
#define CHW (C * HW)
#define TOTAL_TERMS 47279376.0f   // NB * 81 * HP*HP

#define NBLOCKS 2304         // 147456 pixel-groups / 64

// number of kernel-offsets a in [0,2] with 0 <= a+d <= 2 and 0 <= p-a <= HP-1
__device__ __forceinline__ int multv(int p, int d) {
    int lo = max(max(0, -d), p - (HP - 1));
    int hi = min(min(2, 2 - d), p);
    return max(0, hi - lo + 1);
}

__device__ __forceinline__ float bce_fast(float x, float y) {
    // max(x,0) - x*y + log1p(exp(-|x|)), fast-math variant
    float t = __expf(-fabsf(x));
    return fmaxf(x, 0.0f) - x * y + __logf(1.0f + t);
}

// Block = 64 pixel-groups (4 px each; lane = group), 4 waves:
//   wid&1 (par): 0 -> offsets (0,0),(0,1),(0,2),(2,-2..2) [loads rows 0,2; 5 f4]
//                1 -> offsets (1,-2..2)                   [loads rows 0,1; 4 f4]
//   wid>>1 (chalf): channels [0,10) or [10,19) — compile-time bounds.
// chalf-1 waves publish partial dots to LDS (float4, lane-consecutive =
// conflict-free); chalf-0 waves add them and do the BCE epilogue.
// All branches wave-uniform. Grid: 2304 blocks -> 9216 waves (9/SIMD).
__global__ __launch_bounds__(256) void affinity_partial(
        const float* __restrict__ logits,
        const int* __restrict__ labels,
        float* __restrict__ partial) {
    const int t     = threadIdx.x;
    const int lane  = t & 63;
    const int wid   = t >> 6;
    const int par   = wid & 1;
    const int chalf = wid >> 1;

    // XCD-chunk swizzle: 2304 blocks -> 8 chunks of 288 contiguous blocks
    const int b   = blockIdx.x;
    const int blk = (b & 7) * (NBLOCKS / 8) + (b >> 3);
    const int g   = blk * 64 + lane;
    const int px0 = (g % 96) * 4;
    const int rs  = g / 96;
    const int py  = rs % H;
    const int n   = rs / H;

    // slot invariant: f4 at +d1 -> cols px0..px0+3, +d2 -> px0+4..px0+7,
    // +0 -> px0-4..px0-1 (valid when px0>=4; else only weight-0 terms read it)
    const int x0c = max(0, px0 - 4);
    const int d1  = px0 - x0c;                 // 0 or 4
    const int d2  = min(W - 4, px0 + 4) - x0c; // 4 or 8
    const int ro1 = (min(py + 1, H - 1) - py) * W;
    const int ro2 = (min(py + 2, H - 1) - py) * W;

    const float* p0 = logits + (size_t)n * CHW + (size_t)py * W + x0c;

    __shared__ __align__(16) float comb[13 * 256];   // 13312 B

    float acc[32];
#pragma unroll
    for (int k = 0; k < 32; ++k) acc[k] = 0.0f;

#define PAR0_LOOP(CB, CE)                                                 \
    for (int c = (CB); c < (CE); ++c) {                                   \
        const float* pr = p0 + (size_t)c * HW;                            \
        float a[8], e[12];                                                \
        *(float4*)&a[0] = *(const float4*)(pr + d1);                      \
        *(float4*)&a[4] = *(const float4*)(pr + d2);                      \
        *(float4*)&e[0] = *(const float4*)(pr + ro2);                     \
        *(float4*)&e[4] = *(const float4*)(pr + ro2 + d1);                \
        *(float4*)&e[8] = *(const float4*)(pr + ro2 + d2);                \
        _Pragma("unroll")                                                 \
        for (int i = 0; i < 4; ++i) {                                     \
            const float s = a[i];                                         \
            acc[i * 8 + 0] += s * s;                                      \
            acc[i * 8 + 1] += s * a[i + 1];                               \
            acc[i * 8 + 2] += s * a[i + 2];                               \
            _Pragma("unroll")                                             \
            for (int dxi = 0; dxi < 5; ++dxi)                             \
                acc[i * 8 + 3 + dxi] += s * e[2 + i + dxi];               \
        }                                                                 \
    }

#define PAR1_LOOP(CB, CE)                                                 \
    for (int c = (CB); c < (CE); ++c) {                                   \
        const float* pr = p0 + (size_t)c * HW;                            \
        float sa[4], bb[12];                                              \
        *(float4*)&sa[0] = *(const float4*)(pr + d1);                     \
        *(float4*)&bb[0] = *(const float4*)(pr + ro1);                    \
        *(float4*)&bb[4] = *(const float4*)(pr + ro1 + d1);               \
        *(float4*)&bb[8] = *(const float4*)(pr + ro1 + d2);               \
        _Pragma("unroll")                                                 \
        for (int i = 0; i < 4; ++i) {                                     \
            const float s = sa[i];                                        \
            _Pragma("unroll")                                             \
            for (int dxi = 0; dxi < 5; ++dxi)                             \
                acc[i * 5 + dxi] += s * bb[2 + i + dxi];                  \
        }                                                                 \
    }

    if (par == 0) {
        if (chalf == 0) { PAR0_LOOP(0, 10) } else { PAR0_LOOP(10, 19) }
    } else {
        if (chalf == 0) { PAR1_LOOP(0, 10) } else { PAR1_LOOP(10, 19) }
    }

    // chalf-1 waves publish partials (float4, lane-consecutive: conflict-free)
    if (wid == 2) {
#pragma unroll
        for (int q = 0; q < 8; ++q) {
            float4 v = make_float4(acc[4 * q], acc[4 * q + 1],
                                   acc[4 * q + 2], acc[4 * q + 3]);
            *(float4*)&comb[(q * 64 + lane) * 4] = v;
        }
    } else if (wid == 3) {
#pragma unroll
        for (int q = 0; q < 5; ++q) {
            float4 v = make_float4(acc[4 * q], acc[4 * q + 1],
                                   acc[4 * q + 2], acc[4 * q + 3]);
            *(float4*)&comb[((8 + q) * 64 + lane) * 4] = v;
        }
    }
    __syncthreads();

    float total = 0.0f;
    const int* lb0 = labels + (size_t)n * HW + (size_t)py * W + x0c;

    if (wid == 0) {
#pragma unroll
        for (int q = 0; q < 8; ++q) {
            float4 v = *(const float4*)&comb[(q * 64 + lane) * 4];
            acc[4 * q]     += v.x;
            acc[4 * q + 1] += v.y;
            acc[4 * q + 2] += v.z;
            acc[4 * q + 3] += v.w;
        }

        int la[8], ler[12];
        *(int4*)&la[0]  = *(const int4*)(lb0 + d1);   // cols px0..px0+3
        *(int4*)&la[4]  = *(const int4*)(lb0 + d2);   // cols px0+4..px0+7
        *(int4*)&ler[0] = *(const int4*)(lb0 + ro2);
        *(int4*)&ler[4] = *(const int4*)(lb0 + ro2 + d1);
        *(int4*)&ler[8] = *(const int4*)(lb0 + ro2 + d2);

        const int wy0 = multv(py, 0);
        const int wy2 = multv(py, 2);
#pragma unroll
        for (int i = 0; i < 4; ++i) {
            const int px = px0 + i;
            int wx[5];
#pragma unroll
            for (int dxi = 0; dxi < 5; ++dxi) wx[dxi] = multv(px, dxi - 2);
            const int ls = la[i];
            total += (float)(wy0 * wx[2]) * bce_fast(acc[i * 8 + 0], 1.0f);
            total += 2.0f * (float)(wy0 * wx[3]) *
                     bce_fast(acc[i * 8 + 1], (ls == la[i + 1]) ? 1.0f : 0.0f);
            total += 2.0f * (float)(wy0 * wx[4]) *
                     bce_fast(acc[i * 8 + 2], (ls == la[i + 2]) ? 1.0f : 0.0f);
#pragma unroll
            for (int dxi = 0; dxi < 5; ++dxi)
                total += 2.0f * (float)(wy2 * wx[dxi]) *
                         bce_fast(acc[i * 8 + 3 + dxi],
                                  (ls == ler[2 + i + dxi]) ? 1.0f : 0.0f);
        }
    } else if (wid == 1) {
#pragma unroll
        for (int q = 0; q < 5; ++q) {
            float4 v = *(const float4*)&comb[((8 + q) * 64 + lane) * 4];
            acc[4 * q]     += v.x;
            acc[4 * q + 1] += v.y;
            acc[4 * q + 2] += v.z;
            acc[4 * q + 3] += v.w;
        }

        int la4[4], lbr[12];
        *(int4*)&la4[0] = *(const int4*)(lb0 + d1);
        *(int4*)&lbr[0] = *(const int4*)(lb0 + ro1);
        *(int4*)&lbr[4] = *(const int4*)(lb0 + ro1 + d1);
        *(int4*)&lbr[8] = *(const int4*)(lb0 + ro1 + d2);

        const int wy1 = multv(py, 1);
#pragma unroll
        for (int i = 0; i < 4; ++i) {
            const int px = px0 + i;
            int wx[5];
#pragma unroll
            for (int dxi = 0; dxi < 5; ++dxi) wx[dxi] = multv(px, dxi - 2);
            const int ls = la4[i];
#pragma unroll
            for (int dxi = 0; dxi < 5; ++dxi)
                total += 2.0f * (float)(wy1 * wx[dxi]) *
                         bce_fast(acc[i * 5 + dxi],
                                  (ls == lbr[2 + i + dxi]) ? 1.0f : 0.0f);
        }
    }

    // block reduction (waves 2,3 contribute 0)
#pragma unroll
    for (int off = 32; off > 0; off >>= 1) total += __shfl_down(total, off, 64);
    __shared__ float sm[4];
    if (lane == 0) sm[wid] = total;
    __syncthreads();
    if (t == 0)
        partial[blockIdx.x] = sm[0] + sm[1] + sm[2] + sm[3];
}

__global__ __launch_bounds__(256) void reduce_final(
        const float* __restrict__ partial, int n, float* __restrict__ out) {
    float s = 0.0f;
    for (int i = threadIdx.x; i < n; i += 256) s += partial[i];
#pragma unroll
    for (int off = 32; off > 0; off >>= 1) s += __shfl_down(s, off, 64);
    __shared__ float sm[4];
    const int lane = threadIdx.x & 63, wid = threadIdx.x >> 6;
    if (lane == 0) sm[wid] = s;
    __syncthreads();
    if (threadIdx.x == 0)
        out[0] = (sm[0] + sm[1] + sm[2] + sm[3]) / TOTAL_TERMS;
}

extern "C" void kernel_launch(void* const* d_in, const int* in_sizes, int n_in,
                              void* d_out, int out_size, void* d_ws, size_t ws_size,
                              hipStream_t stream) {
    const float* logits = (const float*)d_in[0];
    const int*   labels = (const int*)d_in[1];
    float* out     = (float*)d_out;
    float* partial = (float*)d_ws;   // 2304 floats

    affinity_partial<<<NBLOCKS, 256, 0, stream>>>(logits, labels, partial);
    reduce_final<<<1, 256, 0, stream>>>(partial, NBLOCKS, out);
}